// Round 6
// baseline (646.154 us; speedup 1.0000x reference)
//
#include <hip/hip_runtime.h>
#include <hip/hip_cooperative_groups.h>
#include <stdint.h>

namespace cg = cooperative_groups;

#define Bn 16
#define Sn 256
#define Vn 21128
#define NV4 5282      // Vn/4 exactly
#define RANKn 32
#define BEAMn 64
#define HBINS 4096
#define CAPn 512
#define NSEG 32
#define SEGLEN 8
#define LOG2E 1.44269504088896340736f
#define LN2   0.69314718055994530942f

// v_exp_f32 / v_log_f32 are base-2:
#define EXP2F(x) __builtin_amdgcn_exp2f(x)
#define LOG2F(x) __builtin_amdgcn_logf(x)

__device__ __forceinline__ unsigned f2o(unsigned b) {  // float bits -> order-preserving uint
    return (b & 0x80000000u) ? ~b : (b | 0x80000000u);
}
__device__ __forceinline__ float o2f(unsigned u) {
    unsigned b = (u & 0x80000000u) ? (u ^ 0x80000000u) : ~u;
    return __uint_as_float(b);
}
__device__ __forceinline__ float dot4(float4 a, float4 b) {
    return a.x * b.x + a.y * b.y + a.z * b.z + a.w * b.w;
}

// One block per (b,s) row: exact top-64, force-include target. Fast path:
// fixed threshold THR=2.5 (~131 candidates for N(0,1) rows); exact radix
// fallback otherwise. Tail (t==0): numerator contribution for this row
// (em[tgt] + masked transition dot), atomicAdd to out — replaces num_kernel.
__global__ __launch_bounds__(256) void topk_kernel(const float* __restrict__ emis,
                                                   const int* __restrict__ targets,
                                                   const int* __restrict__ mask,
                                                   const float* __restrict__ E1,
                                                   const float* __restrict__ E2,
                                                   int* __restrict__ beam_idx,
                                                   float* __restrict__ beam_val,
                                                   float* __restrict__ out) {
    const int row = blockIdx.x;            // b*Sn + s
    const float* __restrict__ rowp = emis + (size_t)row * Vn;
    const int tgt = targets[row];
    __shared__ unsigned hist[HBINS];       // fallback only
    __shared__ unsigned csum[256];         // fallback only
    __shared__ unsigned cu[CAPn];
    __shared__ int      cix[CAPn];
    __shared__ int      selidx[BEAMn];
    __shared__ float    selval[BEAMn];
    __shared__ unsigned ccount;
    __shared__ int      binstar;
    __shared__ int      chunkc;
    __shared__ int      hastgt;
    __shared__ unsigned wcnt[4];
    const int t = threadIdx.x;
    if (t == 0) { ccount = 0; hastgt = 0; }

    const unsigned THRU = f2o(__float_as_uint(2.5f));   // order-domain threshold
    uint4 vals[21];
    unsigned cntl = 0;
    #pragma unroll
    for (int it = 0; it < 21; ++it) {
        int v4 = t + it * 256;
        if (v4 < NV4) {
            const uint4 raw = ((const uint4*)rowp)[v4];
            uint4 u;
            u.x = f2o(raw.x); u.y = f2o(raw.y); u.z = f2o(raw.z); u.w = f2o(raw.w);
            vals[it] = u;
            cntl += (u.x > THRU) + (u.y > THRU) + (u.z > THRU) + (u.w > THRU);
        }
    }
    for (int off = 32; off; off >>= 1) cntl += __shfl_xor(cntl, off, 64);
    if ((t & 63) == 0) wcnt[t >> 6] = cntl;
    __syncthreads();
    const unsigned C0 = wcnt[0] + wcnt[1] + wcnt[2] + wcnt[3];

    if (C0 >= BEAMn && C0 <= CAPn) {
        // ---- fast path: compact everything above THR (contains exact top-64)
        #pragma unroll
        for (int it = 0; it < 21; ++it) {
            int v4 = t + it * 256;
            if (v4 < NV4) {
                uint4 u = vals[it];
                int bi = v4 * 4;
                if (u.x > THRU) { unsigned p = atomicAdd(&ccount, 1u); cu[p] = u.x; cix[p] = bi;     }
                if (u.y > THRU) { unsigned p = atomicAdd(&ccount, 1u); cu[p] = u.y; cix[p] = bi + 1; }
                if (u.z > THRU) { unsigned p = atomicAdd(&ccount, 1u); cu[p] = u.z; cix[p] = bi + 2; }
                if (u.w > THRU) { unsigned p = atomicAdd(&ccount, 1u); cu[p] = u.w; cix[p] = bi + 3; }
            }
        }
    } else {
        // ---- exact fallback: 12-bit radix histogram select
        for (int i = t; i < HBINS; i += 256) hist[i] = 0;
        __syncthreads();
        #pragma unroll
        for (int it = 0; it < 21; ++it) {
            int v4 = t + it * 256;
            if (v4 < NV4) {
                uint4 u = vals[it];
                atomicAdd(&hist[u.x >> 20], 1u);
                atomicAdd(&hist[u.y >> 20], 1u);
                atomicAdd(&hist[u.z >> 20], 1u);
                atomicAdd(&hist[u.w >> 20], 1u);
            }
        }
        __syncthreads();
        unsigned cs = 0;
        #pragma unroll
        for (int i = 0; i < 16; ++i) cs += hist[t * 16 + i];
        csum[t] = cs;
        __syncthreads();
        for (int off = 1; off < 256; off <<= 1) {
            unsigned v = csum[t] + ((t + off < 256) ? csum[t + off] : 0u);
            __syncthreads();
            csum[t] = v;
            __syncthreads();
        }
        if (csum[t] >= BEAMn && (t == 255 || csum[t + 1] < BEAMn)) chunkc = t;
        __syncthreads();
        if (t == 0) {
            int tc = chunkc;
            unsigned acc = (tc == 255) ? 0u : csum[tc + 1];
            int bs = tc * 16;
            for (int b2 = tc * 16 + 15; b2 >= tc * 16; --b2) {
                acc += hist[b2];
                if (acc >= BEAMn) { bs = b2; break; }
            }
            binstar = bs;
        }
        __syncthreads();
        const unsigned bstar = (unsigned)binstar;
        #pragma unroll
        for (int it = 0; it < 21; ++it) {
            int v4 = t + it * 256;
            if (v4 < NV4) {
                uint4 u = vals[it];
                int bi = v4 * 4;
                if ((u.x >> 20) >= bstar) { unsigned p = atomicAdd(&ccount, 1u); if (p < CAPn) { cu[p] = u.x; cix[p] = bi;     } }
                if ((u.y >> 20) >= bstar) { unsigned p = atomicAdd(&ccount, 1u); if (p < CAPn) { cu[p] = u.y; cix[p] = bi + 1; } }
                if ((u.z >> 20) >= bstar) { unsigned p = atomicAdd(&ccount, 1u); if (p < CAPn) { cu[p] = u.z; cix[p] = bi + 2; } }
                if ((u.w >> 20) >= bstar) { unsigned p = atomicAdd(&ccount, 1u); if (p < CAPn) { cu[p] = u.w; cix[p] = bi + 3; } }
            }
        }
    }
    __syncthreads();
    const int C = (int)min(ccount, (unsigned)CAPn);
    for (int p = t; p < C; p += 256) {
        unsigned up = cu[p]; int ip = cix[p];
        int rank = 0;
        for (int q = 0; q < C; ++q) {
            unsigned uq = cu[q];
            rank += (uq > up) || (uq == up && cix[q] < ip);
        }
        if (rank < BEAMn) { selidx[rank] = ip; selval[rank] = o2f(up); }
    }
    __syncthreads();
    if (t < BEAMn && selidx[t] == tgt) hastgt = 1;
    __syncthreads();
    if (t == 0 && !hastgt) { selidx[BEAMn - 1] = tgt; selval[BEAMn - 1] = rowp[tgt]; }
    __syncthreads();
    if (t < BEAMn) {
        beam_idx[(size_t)row * BEAMn + t] = selidx[t];
        beam_val[(size_t)row * BEAMn + t] = selval[t];
    }
    // ---- fused numerator tail (was num_kernel)
    if (t == 0) {
        const int s = row & (Sn - 1);
        float val = 0.f;
        if (mask[row]) {
            float em = rowp[tgt];
            float tr = 0.f;
            if (s > 0) {
                int pv = targets[row - 1];
                const float4* p1 = (const float4*)(E1 + (size_t)pv * RANKn);
                const float4* p2 = (const float4*)(E2 + (size_t)tgt * RANKn);
                #pragma unroll
                for (int r = 0; r < 8; ++r) tr += dot4(p1[r], p2[r]);
            }
            val = em + tr;
        }
        atomicAdd(out, val);
    }
}

// ---------------- segprod / finale shared bodies ----------------
#define TPAD 68
struct SegSmem {
    float Qa[64][64], Qb[64][64];
    float Mld[64][68];            // padded: computed-write is 2-way, not 16-way
    float e1t[RANKn][TPAD], e2t[RANKn][TPAD];
    float elog[SEGLEN][64];
    int   mvec[SEGLEN];
    float wred[4];
};
struct FinSmem {
    float us[BEAMn];
    float part[4][BEAMn + 1];
};

// Segment product: seg s of batch b computes P_s = Prod A_k over its 8 steps,
// A_k = mask[k+1] ? M_k * diag(exp(em_{k+1})) : I, with M computed in-kernel.
// NO per-step renorm (growth <= 2^12.7/step * 8 = 2^101 < 2^127); single
// end-of-chain max renorm (log2 offset in segL). First live step writes
// exp2 results straight into Q (I*M == M bit-exactly in f32) — skips one
// Mld round-trip + one 64^3 matmul per chain.
// Storage: segP[seg][j][i] = P_s[i][j] (transposed) for the finale's row reads.
__device__ __forceinline__ void segprod_body(SegSmem& sm, const int blk,
        const float* __restrict__ E1, const float* __restrict__ E2,
        const int* __restrict__ beam_idx, const float* __restrict__ beam_val,
        const int* __restrict__ mask, float* __restrict__ segP,
        float* __restrict__ segL) {
    const int b = blk >> 5, s = blk & 31;
    const int k0 = s * SEGLEN;
    const int nk = min(SEGLEN, (Sn - 1) - k0);   // 8 (7 for last segment)
    const float* __restrict__ bv  = beam_val + (size_t)b * Sn * BEAMn;
    const int* __restrict__ mk   = mask + (size_t)b * Sn;
    const int* __restrict__ bidx = beam_idx + (size_t)b * Sn * BEAMn;
    const int t = threadIdx.x;
    const int ti = t & 15, tj = t >> 4;
    const int i0 = ti * 4, j0 = tj * 4;

    for (int x = t; x < 4096; x += 256)
        (&sm.Qa[0][0])[x] = ((x >> 6) == (x & 63)) ? 1.f : 0.f;  // Q = I (== P^T)
    for (int x = t; x < nk * 64; x += 256)
        sm.elog[x >> 6][x & 63] = bv[(size_t)(k0 + (x >> 6) + 1) * BEAMn + (x & 63)] * LOG2E;
    if (t < nk) sm.mvec[t] = mk[k0 + t + 1];
    __syncthreads();

    float (*Qc)[64] = sm.Qa, (*Qn)[64] = sm.Qb;
    bool qempty = true;                    // block-uniform
    const int srow = t >> 2, sq = t & 3;   // staging: row 0..63, quarter 0..3
    for (int kk = 0; kk < nk; ++kk) {
        const int live = sm.mvec[kk];      // block-uniform
        if (live) {
            // gather E1 rows of beam[k0+kk], E2 rows of beam[k0+kk+1] (transposed)
            const int rb = sq * 8;
            int i1 = bidx[(size_t)(k0 + kk) * BEAMn + srow];
            const float4* s1 = (const float4*)(E1 + (size_t)i1 * RANKn) + sq * 2;
            float4 a0 = s1[0], a1 = s1[1];
            int i2 = bidx[(size_t)(k0 + kk + 1) * BEAMn + srow];
            const float4* s2 = (const float4*)(E2 + (size_t)i2 * RANKn) + sq * 2;
            float4 b0 = s2[0], b1 = s2[1];
            sm.e1t[rb + 0][srow] = a0.x; sm.e1t[rb + 1][srow] = a0.y; sm.e1t[rb + 2][srow] = a0.z; sm.e1t[rb + 3][srow] = a0.w;
            sm.e1t[rb + 4][srow] = a1.x; sm.e1t[rb + 5][srow] = a1.y; sm.e1t[rb + 6][srow] = a1.z; sm.e1t[rb + 7][srow] = a1.w;
            sm.e2t[rb + 0][srow] = b0.x; sm.e2t[rb + 1][srow] = b0.y; sm.e2t[rb + 2][srow] = b0.z; sm.e2t[rb + 3][srow] = b0.w;
            sm.e2t[rb + 4][srow] = b1.x; sm.e2t[rb + 5][srow] = b1.y; sm.e2t[rb + 6][srow] = b1.z; sm.e2t[rb + 7][srow] = b1.w;
        }
        __syncthreads();
        if (live) {
            // M-compute: M[i][j] = exp2( dot*LOG2E + elog[kk][j] )
            float macc[4][4] = {};
            #pragma unroll
            for (int r = 0; r < RANKn; ++r) {
                float4 a  = *(const float4*)&sm.e1t[r][i0];
                float4 bb = *(const float4*)&sm.e2t[r][j0];
                macc[0][0] += a.x * bb.x; macc[0][1] += a.x * bb.y; macc[0][2] += a.x * bb.z; macc[0][3] += a.x * bb.w;
                macc[1][0] += a.y * bb.x; macc[1][1] += a.y * bb.y; macc[1][2] += a.y * bb.z; macc[1][3] += a.y * bb.w;
                macc[2][0] += a.z * bb.x; macc[2][1] += a.z * bb.y; macc[2][2] += a.z * bb.z; macc[2][3] += a.z * bb.w;
                macc[3][0] += a.w * bb.x; macc[3][1] += a.w * bb.y; macc[3][2] += a.w * bb.z; macc[3][3] += a.w * bb.w;
            }
            const float4 el = *(const float4*)&sm.elog[kk][j0];
            float4 ex[4];
            #pragma unroll
            for (int ii = 0; ii < 4; ++ii) {
                ex[ii].x = EXP2F(macc[ii][0] * LOG2E + el.x);
                ex[ii].y = EXP2F(macc[ii][1] * LOG2E + el.y);
                ex[ii].z = EXP2F(macc[ii][2] * LOG2E + el.z);
                ex[ii].w = EXP2F(macc[ii][3] * LOG2E + el.w);
            }
            if (qempty) {
                // first live step: Q := M directly (transposed storage), skip matmul
                float4 w0 = { ex[0].x, ex[1].x, ex[2].x, ex[3].x };
                float4 w1 = { ex[0].y, ex[1].y, ex[2].y, ex[3].y };
                float4 w2 = { ex[0].z, ex[1].z, ex[2].z, ex[3].z };
                float4 w3 = { ex[0].w, ex[1].w, ex[2].w, ex[3].w };
                *(float4*)&Qn[j0 + 0][i0] = w0;
                *(float4*)&Qn[j0 + 1][i0] = w1;
                *(float4*)&Qn[j0 + 2][i0] = w2;
                *(float4*)&Qn[j0 + 3][i0] = w3;
            } else {
                #pragma unroll
                for (int ii = 0; ii < 4; ++ii)
                    *(float4*)&sm.Mld[i0 + ii][j0] = ex[ii];
            }
        }
        __syncthreads();
        if (live) {
            if (!qempty) {
                float acc[4][4] = {};
                for (int r = 0; r < 64; ++r) {
                    float4 a  = *(const float4*)&Qc[r][i0];
                    float4 bb = *(const float4*)&sm.Mld[r][j0];
                    acc[0][0] += a.x * bb.x; acc[0][1] += a.x * bb.y; acc[0][2] += a.x * bb.z; acc[0][3] += a.x * bb.w;
                    acc[1][0] += a.y * bb.x; acc[1][1] += a.y * bb.y; acc[1][2] += a.y * bb.z; acc[1][3] += a.y * bb.w;
                    acc[2][0] += a.z * bb.x; acc[2][1] += a.z * bb.y; acc[2][2] += a.z * bb.z; acc[2][3] += a.z * bb.w;
                    acc[3][0] += a.w * bb.x; acc[3][1] += a.w * bb.y; acc[3][2] += a.w * bb.z; acc[3][3] += a.w * bb.w;
                }
                #pragma unroll
                for (int jj = 0; jj < 4; ++jj) {
                    float4 w = { acc[0][jj], acc[1][jj], acc[2][jj], acc[3][jj] };
                    *(float4*)&Qn[j0 + jj][i0] = w;   // Qn[j][i] = (P*A)[i][j]
                }
            }
            float (*tmp)[64] = Qc; Qc = Qn; Qn = tmp;
            qempty = false;
        }
        __syncthreads();
    }
    // single end-of-chain renorm: m = max(Q), store Q/m, segL = log2(m)
    float lm = 0.f;
    for (int x = t; x < 4096; x += 256) lm = fmaxf(lm, (&Qc[0][0])[x]);
    for (int off = 32; off; off >>= 1) lm = fmaxf(lm, __shfl_xor(lm, off, 64));
    if ((t & 63) == 0) sm.wred[t >> 6] = lm;
    __syncthreads();
    const float m = fmaxf(fmaxf(sm.wred[0], sm.wred[1]), fmaxf(sm.wred[2], sm.wred[3]));
    const float inv = 1.f / m;
    float* op = segP + (size_t)blk * 4096;
    for (int x = t; x < 4096; x += 256) op[x] = (&Qc[0][0])[x] * inv;
    if (t == 0) segL[blk] = LOG2F(m);
}

// Finale: u = exp2(score0), then NSEG sequential matvecs u <- u * P_s (with
// register prefetch of the next segment's rows), logsumexp at the end.
__device__ __forceinline__ void finale_body(FinSmem& fm, const int b,
        const float* __restrict__ segP, const float* __restrict__ segL,
        const float* __restrict__ beam_val, float* __restrict__ out) {
    const int t = threadIdx.x;
    const int w = t >> 6, j = t & 63;
    const float* __restrict__ bv = beam_val + (size_t)b * Sn * BEAMn;
    float sc = bv[j] * LOG2E;                    // log2-domain score0, replicated per wave
    float mx = sc;
    for (int off = 32; off; off >>= 1) mx = fmaxf(mx, __shfl_xor(mx, off, 64));
    float u = EXP2F(sc - mx);
    float Ltot = mx;
    const float* p0 = segP + ((size_t)b * NSEG) * 4096 + (size_t)j * 64 + w * 16;
    float4 ra0 = ((const float4*)p0)[0], ra1 = ((const float4*)p0)[1],
           ra2 = ((const float4*)p0)[2], ra3 = ((const float4*)p0)[3];
    for (int s2 = 0; s2 < NSEG; ++s2) {
        float4 rb0, rb1, rb2, rb3;
        if (s2 + 1 < NSEG) {
            const float* pn = segP + ((size_t)b * NSEG + s2 + 1) * 4096 + (size_t)j * 64 + w * 16;
            rb0 = ((const float4*)pn)[0]; rb1 = ((const float4*)pn)[1];
            rb2 = ((const float4*)pn)[2]; rb3 = ((const float4*)pn)[3];
        }
        if (w == 0) fm.us[j] = u;
        __syncthreads();
        const float4* uu = (const float4*)&fm.us[w * 16];
        float a2 = dot4(ra0, uu[0]) + dot4(ra1, uu[1]) + dot4(ra2, uu[2]) + dot4(ra3, uu[3]);
        fm.part[w][j] = a2;
        __syncthreads();
        float tot = fm.part[0][j] + fm.part[1][j] + fm.part[2][j] + fm.part[3][j];
        float m = tot;
        for (int off = 32; off; off >>= 1) m = fmaxf(m, __shfl_xor(m, off, 64));
        u = tot / m;
        Ltot += LOG2F(m) + segL[b * NSEG + s2];
        ra0 = rb0; ra1 = rb1; ra2 = rb2; ra3 = rb3;
    }
    if (t < BEAMn) {                              // wave 0
        float e = u;
        for (int off = 32; off; off >>= 1) e += __shfl_xor(e, off, 64);
        if (t == 0) atomicAdd(out, -LN2 * (Ltot + LOG2F(e)));
    }
}

// ---------------- kernels ----------------
// Cooperative fused version: 512 blocks = 2/CU exactly (LDS ~70 KB, bounds(256,2)).
__global__ __launch_bounds__(256, 2) void segfin_kernel(const float* __restrict__ E1,
                                                        const float* __restrict__ E2,
                                                        const int* __restrict__ beam_idx,
                                                        const float* __restrict__ beam_val,
                                                        const int* __restrict__ mask,
                                                        float* __restrict__ segP,
                                                        float* __restrict__ segL,
                                                        float* __restrict__ out) {
    __shared__ SegSmem sm;
    __shared__ FinSmem fm;
    segprod_body(sm, blockIdx.x, E1, E2, beam_idx, beam_val, mask, segP, segL);
    cg::this_grid().sync();
    if (blockIdx.x < Bn)
        finale_body(fm, blockIdx.x, segP, segL, beam_val, out);
}

// Fallback pair (same bodies, separate launches) if cooperative launch fails.
__global__ __launch_bounds__(256, 2) void segprod_kernel(const float* __restrict__ E1,
                                                         const float* __restrict__ E2,
                                                         const int* __restrict__ beam_idx,
                                                         const float* __restrict__ beam_val,
                                                         const int* __restrict__ mask,
                                                         float* __restrict__ segP,
                                                         float* __restrict__ segL) {
    __shared__ SegSmem sm;
    segprod_body(sm, blockIdx.x, E1, E2, beam_idx, beam_val, mask, segP, segL);
}

__global__ __launch_bounds__(256) void finale_kernel(const float* __restrict__ segP,
                                                     const float* __restrict__ segL,
                                                     const float* __restrict__ beam_val,
                                                     float* __restrict__ out) {
    __shared__ FinSmem fm;
    finale_body(fm, blockIdx.x, segP, segL, beam_val, out);
}

extern "C" void kernel_launch(void* const* d_in, const int* in_sizes, int n_in,
                              void* d_out, int out_size, void* d_ws, size_t ws_size,
                              hipStream_t stream) {
    const float* emis    = (const float*)d_in[0];
    const int*   targets = (const int*)d_in[1];
    const int*   mask    = (const int*)d_in[2];   // bool input delivered as int32
    const float* E1      = (const float*)d_in[3];
    const float* E2      = (const float*)d_in[4];
    float* out = (float*)d_out;
    char* ws = (char*)d_ws;
    int*   beam_idx = (int*)ws;                          // 1 MB
    float* beam_val = (float*)(ws + (1 << 20));          // 1 MB
    float* segP     = (float*)(ws + (2 << 20));          // 16*32*4096*4 = 8 MB
    float* segL     = (float*)(ws + (10 << 20));         // 2 KB

    (void)hipMemsetAsync(out, 0, sizeof(float), stream);
    hipLaunchKernelGGL(topk_kernel, dim3(Bn * Sn), dim3(256), 0, stream,
                       emis, targets, mask, E1, E2, beam_idx, beam_val, out);

    void* kargs[] = { (void*)&E1, (void*)&E2, (void*)&beam_idx, (void*)&beam_val,
                      (void*)&mask, (void*)&segP, (void*)&segL, (void*)&out };
    hipError_t ce = hipLaunchCooperativeKernel(reinterpret_cast<void*>(segfin_kernel),
                                               dim3(Bn * NSEG), dim3(256), kargs, 0, stream);
    if (ce != hipSuccess) {
        // clean fallback: proven two-kernel pair
        hipLaunchKernelGGL(segprod_kernel, dim3(Bn * NSEG), dim3(256), 0, stream,
                           E1, E2, beam_idx, beam_val, mask, segP, segL);
        hipLaunchKernelGGL(finale_kernel, dim3(Bn), dim3(256), 0, stream,
                           segP, segL, beam_val, out);
    }
}

// Round 7
// 564.117 us; speedup vs baseline: 1.1454x; 1.1454x over previous
//
#include <hip/hip_runtime.h>
#include <stdint.h>

#define Bn 16
#define Sn 256
#define Vn 21128
#define NV4 5282      // Vn/4 exactly
#define RANKn 32
#define BEAMn 64
#define HBINS 4096
#define CAPn 512
#define NSEG 32
#define SEGLEN 8
#define LOG2E 1.44269504088896340736f
#define LN2   0.69314718055994530942f

// v_exp_f32 / v_log_f32 are base-2:
#define EXP2F(x) __builtin_amdgcn_exp2f(x)
#define LOG2F(x) __builtin_amdgcn_logf(x)

__device__ __forceinline__ unsigned f2o(unsigned b) {  // float bits -> order-preserving uint
    return (b & 0x80000000u) ? ~b : (b | 0x80000000u);
}
__device__ __forceinline__ float o2f(unsigned u) {
    unsigned b = (u & 0x80000000u) ? (u ^ 0x80000000u) : ~u;
    return __uint_as_float(b);
}
__device__ __forceinline__ float dot4(float4 a, float4 b) {
    return a.x * b.x + a.y * b.y + a.z * b.z + a.w * b.w;
}

// One block per (b,s) row: exact top-64, force-include target. Fast path:
// fixed threshold THR=2.5 (~131 candidates for N(0,1) rows); exact radix
// fallback otherwise. Tail (t==0): numerator contribution for this row
// (em[tgt] + masked transition dot), atomicAdd to out — replaces num_kernel.
__global__ __launch_bounds__(256) void topk_kernel(const float* __restrict__ emis,
                                                   const int* __restrict__ targets,
                                                   const int* __restrict__ mask,
                                                   const float* __restrict__ E1,
                                                   const float* __restrict__ E2,
                                                   int* __restrict__ beam_idx,
                                                   float* __restrict__ beam_val,
                                                   float* __restrict__ out) {
    const int row = blockIdx.x;            // b*Sn + s
    const float* __restrict__ rowp = emis + (size_t)row * Vn;
    const int tgt = targets[row];
    __shared__ unsigned hist[HBINS];       // fallback only
    __shared__ unsigned csum[256];         // fallback only
    __shared__ unsigned cu[CAPn];
    __shared__ int      cix[CAPn];
    __shared__ int      selidx[BEAMn];
    __shared__ float    selval[BEAMn];
    __shared__ unsigned ccount;
    __shared__ int      binstar;
    __shared__ int      chunkc;
    __shared__ int      hastgt;
    __shared__ unsigned wcnt[4];
    const int t = threadIdx.x;
    if (t == 0) { ccount = 0; hastgt = 0; }

    const unsigned THRU = f2o(__float_as_uint(2.5f));   // order-domain threshold
    uint4 vals[21];
    unsigned cntl = 0;
    #pragma unroll
    for (int it = 0; it < 21; ++it) {
        int v4 = t + it * 256;
        if (v4 < NV4) {
            const uint4 raw = ((const uint4*)rowp)[v4];
            uint4 u;
            u.x = f2o(raw.x); u.y = f2o(raw.y); u.z = f2o(raw.z); u.w = f2o(raw.w);
            vals[it] = u;
            cntl += (u.x > THRU) + (u.y > THRU) + (u.z > THRU) + (u.w > THRU);
        }
    }
    for (int off = 32; off; off >>= 1) cntl += __shfl_xor(cntl, off, 64);
    if ((t & 63) == 0) wcnt[t >> 6] = cntl;
    __syncthreads();
    const unsigned C0 = wcnt[0] + wcnt[1] + wcnt[2] + wcnt[3];

    if (C0 >= BEAMn && C0 <= CAPn) {
        // ---- fast path: compact everything above THR (contains exact top-64)
        #pragma unroll
        for (int it = 0; it < 21; ++it) {
            int v4 = t + it * 256;
            if (v4 < NV4) {
                uint4 u = vals[it];
                int bi = v4 * 4;
                if (u.x > THRU) { unsigned p = atomicAdd(&ccount, 1u); cu[p] = u.x; cix[p] = bi;     }
                if (u.y > THRU) { unsigned p = atomicAdd(&ccount, 1u); cu[p] = u.y; cix[p] = bi + 1; }
                if (u.z > THRU) { unsigned p = atomicAdd(&ccount, 1u); cu[p] = u.z; cix[p] = bi + 2; }
                if (u.w > THRU) { unsigned p = atomicAdd(&ccount, 1u); cu[p] = u.w; cix[p] = bi + 3; }
            }
        }
    } else {
        // ---- exact fallback: 12-bit radix histogram select
        for (int i = t; i < HBINS; i += 256) hist[i] = 0;
        __syncthreads();
        #pragma unroll
        for (int it = 0; it < 21; ++it) {
            int v4 = t + it * 256;
            if (v4 < NV4) {
                uint4 u = vals[it];
                atomicAdd(&hist[u.x >> 20], 1u);
                atomicAdd(&hist[u.y >> 20], 1u);
                atomicAdd(&hist[u.z >> 20], 1u);
                atomicAdd(&hist[u.w >> 20], 1u);
            }
        }
        __syncthreads();
        unsigned cs = 0;
        #pragma unroll
        for (int i = 0; i < 16; ++i) cs += hist[t * 16 + i];
        csum[t] = cs;
        __syncthreads();
        for (int off = 1; off < 256; off <<= 1) {
            unsigned v = csum[t] + ((t + off < 256) ? csum[t + off] : 0u);
            __syncthreads();
            csum[t] = v;
            __syncthreads();
        }
        if (csum[t] >= BEAMn && (t == 255 || csum[t + 1] < BEAMn)) chunkc = t;
        __syncthreads();
        if (t == 0) {
            int tc = chunkc;
            unsigned acc = (tc == 255) ? 0u : csum[tc + 1];
            int bs = tc * 16;
            for (int b2 = tc * 16 + 15; b2 >= tc * 16; --b2) {
                acc += hist[b2];
                if (acc >= BEAMn) { bs = b2; break; }
            }
            binstar = bs;
        }
        __syncthreads();
        const unsigned bstar = (unsigned)binstar;
        #pragma unroll
        for (int it = 0; it < 21; ++it) {
            int v4 = t + it * 256;
            if (v4 < NV4) {
                uint4 u = vals[it];
                int bi = v4 * 4;
                if ((u.x >> 20) >= bstar) { unsigned p = atomicAdd(&ccount, 1u); if (p < CAPn) { cu[p] = u.x; cix[p] = bi;     } }
                if ((u.y >> 20) >= bstar) { unsigned p = atomicAdd(&ccount, 1u); if (p < CAPn) { cu[p] = u.y; cix[p] = bi + 1; } }
                if ((u.z >> 20) >= bstar) { unsigned p = atomicAdd(&ccount, 1u); if (p < CAPn) { cu[p] = u.z; cix[p] = bi + 2; } }
                if ((u.w >> 20) >= bstar) { unsigned p = atomicAdd(&ccount, 1u); if (p < CAPn) { cu[p] = u.w; cix[p] = bi + 3; } }
            }
        }
    }
    __syncthreads();
    const int C = (int)min(ccount, (unsigned)CAPn);
    for (int p = t; p < C; p += 256) {
        unsigned up = cu[p]; int ip = cix[p];
        int rank = 0;
        for (int q = 0; q < C; ++q) {
            unsigned uq = cu[q];
            rank += (uq > up) || (uq == up && cix[q] < ip);
        }
        if (rank < BEAMn) { selidx[rank] = ip; selval[rank] = o2f(up); }
    }
    __syncthreads();
    if (t < BEAMn && selidx[t] == tgt) hastgt = 1;
    __syncthreads();
    if (t == 0 && !hastgt) { selidx[BEAMn - 1] = tgt; selval[BEAMn - 1] = rowp[tgt]; }
    __syncthreads();
    if (t < BEAMn) {
        beam_idx[(size_t)row * BEAMn + t] = selidx[t];
        beam_val[(size_t)row * BEAMn + t] = selval[t];
    }
    // ---- fused numerator tail (was num_kernel)
    if (t == 0) {
        const int s = row & (Sn - 1);
        float val = 0.f;
        if (mask[row]) {
            float em = rowp[tgt];
            float tr = 0.f;
            if (s > 0) {
                int pv = targets[row - 1];
                const float4* p1 = (const float4*)(E1 + (size_t)pv * RANKn);
                const float4* p2 = (const float4*)(E2 + (size_t)tgt * RANKn);
                #pragma unroll
                for (int r = 0; r < 8; ++r) tr += dot4(p1[r], p2[r]);
            }
            val = em + tr;
        }
        atomicAdd(out, val);
    }
}

// Fused trans+segprod: seg s of batch b computes P_s = Prod A_k over its 8 steps,
// A_k = mask[k+1] ? M_k * diag(exp(em_{k+1})) : I, with M computed in-kernel.
// NO per-step renorm (growth <= 2^12.7/step * 8 = 2^101 < 2^127); single
// end-of-chain max renorm (log2 offset in segL). First live step writes
// exp2 results straight into Q (I*M == M bit-exactly in f32) — skips one
// Mld round-trip + one 64^3 matmul per chain.
// 2 blocks/CU (LDS ~70KB, __launch_bounds__(256,2)) so barrier stalls of one
// block hide under the other.
// Storage: segP[seg][j][i] = P_s[i][j] (transposed) for the finale's row reads.
#define TPAD 68
__global__ __launch_bounds__(256, 2) void segprod_kernel(const float* __restrict__ E1,
                                                         const float* __restrict__ E2,
                                                         const int* __restrict__ beam_idx,
                                                         const float* __restrict__ beam_val,
                                                         const int* __restrict__ mask,
                                                         float* __restrict__ segP,
                                                         float* __restrict__ segL) {
    const int blk = blockIdx.x;           // b*NSEG + s
    const int b = blk >> 5, s = blk & 31;
    const int k0 = s * SEGLEN;
    const int nk = min(SEGLEN, (Sn - 1) - k0);   // 8 (7 for last segment)
    const float* __restrict__ bv  = beam_val + (size_t)b * Sn * BEAMn;
    const int* __restrict__ mk   = mask + (size_t)b * Sn;
    const int* __restrict__ bidx = beam_idx + (size_t)b * Sn * BEAMn;
    __shared__ float Qa[64][64], Qb[64][64];
    __shared__ float Mld[64][68];          // padded: computed-write is 2-way, not 16-way
    __shared__ float e1t[RANKn][TPAD];
    __shared__ float e2t[RANKn][TPAD];
    __shared__ float elog[SEGLEN][64];
    __shared__ int   mvec[SEGLEN];
    __shared__ float wred[4];
    const int t = threadIdx.x;
    const int ti = t & 15, tj = t >> 4;
    const int i0 = ti * 4, j0 = tj * 4;

    for (int x = t; x < 4096; x += 256)
        (&Qa[0][0])[x] = ((x >> 6) == (x & 63)) ? 1.f : 0.f;     // Q = I (== P^T)
    for (int x = t; x < nk * 64; x += 256)
        elog[x >> 6][x & 63] = bv[(size_t)(k0 + (x >> 6) + 1) * BEAMn + (x & 63)] * LOG2E;
    if (t < nk) mvec[t] = mk[k0 + t + 1];
    __syncthreads();

    float (*Qc)[64] = Qa, (*Qn)[64] = Qb;
    bool qempty = true;                    // block-uniform
    const int srow = t >> 2, sq = t & 3;   // staging: row 0..63, quarter 0..3
    for (int kk = 0; kk < nk; ++kk) {
        const int live = mvec[kk];          // block-uniform
        if (live) {
            // gather E1 rows of beam[k0+kk], E2 rows of beam[k0+kk+1] (transposed)
            const int rb = sq * 8;
            int i1 = bidx[(size_t)(k0 + kk) * BEAMn + srow];
            const float4* s1 = (const float4*)(E1 + (size_t)i1 * RANKn) + sq * 2;
            float4 a0 = s1[0], a1 = s1[1];
            int i2 = bidx[(size_t)(k0 + kk + 1) * BEAMn + srow];
            const float4* s2 = (const float4*)(E2 + (size_t)i2 * RANKn) + sq * 2;
            float4 b0 = s2[0], b1 = s2[1];
            e1t[rb + 0][srow] = a0.x; e1t[rb + 1][srow] = a0.y; e1t[rb + 2][srow] = a0.z; e1t[rb + 3][srow] = a0.w;
            e1t[rb + 4][srow] = a1.x; e1t[rb + 5][srow] = a1.y; e1t[rb + 6][srow] = a1.z; e1t[rb + 7][srow] = a1.w;
            e2t[rb + 0][srow] = b0.x; e2t[rb + 1][srow] = b0.y; e2t[rb + 2][srow] = b0.z; e2t[rb + 3][srow] = b0.w;
            e2t[rb + 4][srow] = b1.x; e2t[rb + 5][srow] = b1.y; e2t[rb + 6][srow] = b1.z; e2t[rb + 7][srow] = b1.w;
        }
        __syncthreads();
        if (live) {
            // M-compute: M[i][j] = exp2( dot*LOG2E + elog[kk][j] )
            float macc[4][4] = {};
            #pragma unroll
            for (int r = 0; r < RANKn; ++r) {
                float4 a  = *(const float4*)&e1t[r][i0];
                float4 bb = *(const float4*)&e2t[r][j0];
                macc[0][0] += a.x * bb.x; macc[0][1] += a.x * bb.y; macc[0][2] += a.x * bb.z; macc[0][3] += a.x * bb.w;
                macc[1][0] += a.y * bb.x; macc[1][1] += a.y * bb.y; macc[1][2] += a.y * bb.z; macc[1][3] += a.y * bb.w;
                macc[2][0] += a.z * bb.x; macc[2][1] += a.z * bb.y; macc[2][2] += a.z * bb.z; macc[2][3] += a.z * bb.w;
                macc[3][0] += a.w * bb.x; macc[3][1] += a.w * bb.y; macc[3][2] += a.w * bb.z; macc[3][3] += a.w * bb.w;
            }
            const float4 el = *(const float4*)&elog[kk][j0];
            float4 ex[4];
            #pragma unroll
            for (int ii = 0; ii < 4; ++ii) {
                ex[ii].x = EXP2F(macc[ii][0] * LOG2E + el.x);
                ex[ii].y = EXP2F(macc[ii][1] * LOG2E + el.y);
                ex[ii].z = EXP2F(macc[ii][2] * LOG2E + el.z);
                ex[ii].w = EXP2F(macc[ii][3] * LOG2E + el.w);
            }
            if (qempty) {
                // first live step: Q := M directly (transposed storage), skip matmul
                float4 w0 = { ex[0].x, ex[1].x, ex[2].x, ex[3].x };
                float4 w1 = { ex[0].y, ex[1].y, ex[2].y, ex[3].y };
                float4 w2 = { ex[0].z, ex[1].z, ex[2].z, ex[3].z };
                float4 w3 = { ex[0].w, ex[1].w, ex[2].w, ex[3].w };
                *(float4*)&Qn[j0 + 0][i0] = w0;
                *(float4*)&Qn[j0 + 1][i0] = w1;
                *(float4*)&Qn[j0 + 2][i0] = w2;
                *(float4*)&Qn[j0 + 3][i0] = w3;
            } else {
                #pragma unroll
                for (int ii = 0; ii < 4; ++ii)
                    *(float4*)&Mld[i0 + ii][j0] = ex[ii];
            }
        }
        __syncthreads();
        if (live) {
            if (!qempty) {
                float acc[4][4] = {};
                for (int r = 0; r < 64; ++r) {
                    float4 a  = *(const float4*)&Qc[r][i0];
                    float4 bb = *(const float4*)&Mld[r][j0];
                    acc[0][0] += a.x * bb.x; acc[0][1] += a.x * bb.y; acc[0][2] += a.x * bb.z; acc[0][3] += a.x * bb.w;
                    acc[1][0] += a.y * bb.x; acc[1][1] += a.y * bb.y; acc[1][2] += a.y * bb.z; acc[1][3] += a.y * bb.w;
                    acc[2][0] += a.z * bb.x; acc[2][1] += a.z * bb.y; acc[2][2] += a.z * bb.z; acc[2][3] += a.z * bb.w;
                    acc[3][0] += a.w * bb.x; acc[3][1] += a.w * bb.y; acc[3][2] += a.w * bb.z; acc[3][3] += a.w * bb.w;
                }
                #pragma unroll
                for (int jj = 0; jj < 4; ++jj) {
                    float4 w = { acc[0][jj], acc[1][jj], acc[2][jj], acc[3][jj] };
                    *(float4*)&Qn[j0 + jj][i0] = w;   // Qn[j][i] = (P*A)[i][j]
                }
            }
            float (*tmp)[64] = Qc; Qc = Qn; Qn = tmp;
            qempty = false;
        }
        __syncthreads();
    }
    // single end-of-chain renorm: m = max(Q), store Q/m, segL = log2(m)
    float lm = 0.f;
    for (int x = t; x < 4096; x += 256) lm = fmaxf(lm, (&Qc[0][0])[x]);
    for (int off = 32; off; off >>= 1) lm = fmaxf(lm, __shfl_xor(lm, off, 64));
    if ((t & 63) == 0) wred[t >> 6] = lm;
    __syncthreads();
    const float m = fmaxf(fmaxf(wred[0], wred[1]), fmaxf(wred[2], wred[3]));
    const float inv = 1.f / m;
    float* op = segP + (size_t)blk * 4096;
    for (int x = t; x < 4096; x += 256) op[x] = (&Qc[0][0])[x] * inv;
    if (t == 0) segL[blk] = LOG2F(m);
}

// Finale: u = exp2(score0), then NSEG sequential matvecs u <- u * P_s (with
// register prefetch of the next segment's rows), logsumexp at the end.
__global__ __launch_bounds__(256) void finale_kernel(const float* __restrict__ segP,
                                                     const float* __restrict__ segL,
                                                     const float* __restrict__ beam_val,
                                                     float* __restrict__ out) {
    const int b = blockIdx.x;
    const int t = threadIdx.x;
    const int w = t >> 6, j = t & 63;
    const float* __restrict__ bv = beam_val + (size_t)b * Sn * BEAMn;
    __shared__ float us[BEAMn];
    __shared__ float part[4][BEAMn + 1];
    float sc = bv[j] * LOG2E;                    // log2-domain score0, replicated per wave
    float mx = sc;
    for (int off = 32; off; off >>= 1) mx = fmaxf(mx, __shfl_xor(mx, off, 64));
    float u = EXP2F(sc - mx);
    float Ltot = mx;
    const float* p0 = segP + ((size_t)b * NSEG) * 4096 + (size_t)j * 64 + w * 16;
    float4 ra0 = ((const float4*)p0)[0], ra1 = ((const float4*)p0)[1],
           ra2 = ((const float4*)p0)[2], ra3 = ((const float4*)p0)[3];
    for (int s2 = 0; s2 < NSEG; ++s2) {
        float4 rb0, rb1, rb2, rb3;
        if (s2 + 1 < NSEG) {
            const float* pn = segP + ((size_t)b * NSEG + s2 + 1) * 4096 + (size_t)j * 64 + w * 16;
            rb0 = ((const float4*)pn)[0]; rb1 = ((const float4*)pn)[1];
            rb2 = ((const float4*)pn)[2]; rb3 = ((const float4*)pn)[3];
        }
        if (w == 0) us[j] = u;
        __syncthreads();
        const float4* uu = (const float4*)&us[w * 16];
        float a2 = dot4(ra0, uu[0]) + dot4(ra1, uu[1]) + dot4(ra2, uu[2]) + dot4(ra3, uu[3]);
        part[w][j] = a2;
        __syncthreads();
        float tot = part[0][j] + part[1][j] + part[2][j] + part[3][j];
        float m = tot;
        for (int off = 32; off; off >>= 1) m = fmaxf(m, __shfl_xor(m, off, 64));
        u = tot / m;
        Ltot += LOG2F(m) + segL[b * NSEG + s2];
        ra0 = rb0; ra1 = rb1; ra2 = rb2; ra3 = rb3;
    }
    if (t < BEAMn) {                              // wave 0
        float e = u;
        for (int off = 32; off; off >>= 1) e += __shfl_xor(e, off, 64);
        if (t == 0) atomicAdd(out, -LN2 * (Ltot + LOG2F(e)));
    }
}

extern "C" void kernel_launch(void* const* d_in, const int* in_sizes, int n_in,
                              void* d_out, int out_size, void* d_ws, size_t ws_size,
                              hipStream_t stream) {
    const float* emis    = (const float*)d_in[0];
    const int*   targets = (const int*)d_in[1];
    const int*   mask    = (const int*)d_in[2];   // bool input delivered as int32
    const float* E1      = (const float*)d_in[3];
    const float* E2      = (const float*)d_in[4];
    float* out = (float*)d_out;
    char* ws = (char*)d_ws;
    int*   beam_idx = (int*)ws;                          // 1 MB
    float* beam_val = (float*)(ws + (1 << 20));          // 1 MB
    float* segP     = (float*)(ws + (2 << 20));          // 16*32*4096*4 = 8 MB
    float* segL     = (float*)(ws + (10 << 20));         // 2 KB

    (void)hipMemsetAsync(out, 0, sizeof(float), stream);
    hipLaunchKernelGGL(topk_kernel, dim3(Bn * Sn), dim3(256), 0, stream,
                       emis, targets, mask, E1, E2, beam_idx, beam_val, out);
    hipLaunchKernelGGL(segprod_kernel, dim3(Bn * NSEG), dim3(256), 0, stream,
                       E1, E2, beam_idx, beam_val, mask, segP, segL);
    hipLaunchKernelGGL(finale_kernel, dim3(Bn), dim3(256), 0, stream,
                       segP, segL, beam_val, out);
}